// Round 1
// baseline (810.283 us; speedup 1.0000x reference)
//
#include <hip/hip_runtime.h>

#define BB   4
#define CIN  3
#define TT   32
#define HH   64
#define WW   64
#define COUT 64

#define LROW   19            // 18 + 1 pad
#define LPLANE (18 * LROW)   // per-cin plane in LDS

__device__ __forceinline__ float fexp2(float x) { return __builtin_amdgcn_exp2f(x); }
__device__ __forceinline__ float frcp(float x)  { return __builtin_amdgcn_rcpf(x); }
__device__ __forceinline__ float fsigmoid(float x) {
    // 1/(1+exp(-x)) ; exp(-x)=2^(-x*log2e)
    return frcp(1.0f + fexp2(x * -1.4426950408889634f));
}
__device__ __forceinline__ float ftanh(float x) {
    // tanh(x) = 2/(1+exp(-2x)) - 1 ; saturates correctly via inf->rcp->0
    return 2.0f * frcp(1.0f + fexp2(x * -2.8853900817779268f)) - 1.0f;
}

__global__ __launch_bounds__(256) void convqrnn_fused(
    const float* __restrict__ X,    // (B,CIN,T,H,W)
    const float* __restrict__ Wc,   // (4*COUT,CIN,2,3,3)
    const float* __restrict__ bc,   // (4*COUT)
    const float* __restrict__ Wci,  // (COUT,H,W)
    const float* __restrict__ Wcf,
    const float* __restrict__ Wco,
    float* __restrict__ out)        // (B,COUT,T,H,W)
{
    __shared__ float sx[CIN * LPLANE];

    const int tid = threadIdx.x;
    const int tx = tid & 15;
    const int ty = tid >> 4;
    const int bx = blockIdx.x;         // 16 tiles: 4x4 over (h,w)
    const int co = blockIdx.y;
    const int b  = blockIdx.z;
    const int h0 = (bx >> 2) * 16;
    const int w0 = (bx & 3) * 16;
    const int h = h0 + ty;
    const int w = w0 + tx;
    const int pix = h * WW + w;

    // peephole params for this pixel
    const float wci = Wci[co * (HH * WW) + pix];
    const float wcf = Wcf[co * (HH * WW) + pix];
    const float wco = Wco[co * (HH * WW) + pix];

    // biases (wave-uniform -> scalar loads)
    const float b0 = bc[0 * COUT + co];
    const float b1 = bc[1 * COUT + co];
    const float b2 = bc[2 * COUT + co];
    const float b3 = bc[3 * COUT + co];

    const float* __restrict__ Xb = X + (size_t)b * (CIN * TT * HH * WW);
    float* __restrict__ outp = out + ((size_t)(b * COUT + co) * TT) * (HH * WW) + pix;

    // weight rows for the 4 gates (wave-uniform pointers)
    const float* __restrict__ wg0 = Wc + (size_t)(0 * COUT + co) * 54;
    const float* __restrict__ wg1 = Wc + (size_t)(1 * COUT + co) * 54;
    const float* __restrict__ wg2 = Wc + (size_t)(2 * COUT + co) * 54;
    const float* __restrict__ wg3 = Wc + (size_t)(3 * COUT + co) * 54;

    float xa[27];   // one time-plane 3x3x3 window in registers
    float xbuf[27];
    #pragma unroll
    for (int j = 0; j < 27; ++j) xa[j] = 0.0f;   // t = -1 plane is zero-pad

    float C = 0.0f;

    const int ldsBase = 0;  // window read base handled by constant offsets

    // one QRNN step: stage plane t into LDS, read window into `cur`,
    // conv with prev(dt=0)+cur(dt=1), recurrence, store.
    auto step = [&](int t, float (&prev)[27], float (&cur)[27]) {
        __syncthreads();   // previous iteration's reads done before overwrite
        // ---- stage plane t: CIN x 18 x 18 halo tile ----
        #pragma unroll
        for (int k = 0; k < 4; ++k) {
            int idx = tid + k * 256;
            if (idx < CIN * 18 * 18) {
                int cin = idx / 324;
                int r   = idx - cin * 324;
                int y   = r / 18;
                int x   = r - y * 18;
                int gh = h0 + y - 1;
                int gw = w0 + x - 1;
                float v = 0.0f;
                if ((unsigned)gh < (unsigned)HH && (unsigned)gw < (unsigned)WW)
                    v = Xb[((size_t)cin * TT + t) * (HH * WW) + gh * WW + gw];
                sx[cin * LPLANE + y * LROW + x] = v;
            }
        }
        __syncthreads();
        // ---- read 3x3x3 window into registers ----
        #pragma unroll
        for (int cin = 0; cin < 3; ++cin)
            #pragma unroll
            for (int kh = 0; kh < 3; ++kh)
                #pragma unroll
                for (int kw = 0; kw < 3; ++kw)
                    cur[cin * 9 + kh * 3 + kw] =
                        sx[ldsBase + cin * LPLANE + (ty + kh) * LROW + (tx + kw)];

        // ---- 4-gate conv: dt=0 uses prev plane, dt=1 uses cur plane ----
        float a0 = b0, a1 = b1, a2 = b2, a3 = b3;
        #pragma unroll
        for (int cin = 0; cin < 3; ++cin) {
            #pragma unroll
            for (int kk = 0; kk < 9; ++kk) {
                const int wi0 = cin * 18 + kk;      // dt=0
                const int wi1 = cin * 18 + 9 + kk;  // dt=1
                const float xp = prev[cin * 9 + kk];
                const float xc = cur[cin * 9 + kk];
                a0 += wg0[wi0] * xp; a0 += wg0[wi1] * xc;
                a1 += wg1[wi0] * xp; a1 += wg1[wi1] * xc;
                a2 += wg2[wi0] * xp; a2 += wg2[wi1] * xc;
                a3 += wg3[wi0] * xp; a3 += wg3[wi1] * xc;
            }
        }

        // ---- recurrence ----
        const float ig = fsigmoid(a0 + wci * C);
        const float fg = fsigmoid(a1 + wcf * C);
        const float Cn = fg * C + ig * ftanh(a2);
        const float og = fsigmoid(a3 + wco * Cn);
        const float Hn = og * ftanh(Cn);
        C = Cn;
        outp[(size_t)t * (HH * WW)] = Hn;
    };

    // double-pumped so prev/cur register arrays alternate with static indices
    for (int t = 0; t < TT; t += 2) {
        step(t,     xa,   xbuf);
        step(t + 1, xbuf, xa);
    }
}

extern "C" void kernel_launch(void* const* d_in, const int* in_sizes, int n_in,
                              void* d_out, int out_size, void* d_ws, size_t ws_size,
                              hipStream_t stream) {
    const float* X   = (const float*)d_in[0];
    const float* Wc  = (const float*)d_in[1];
    const float* bc  = (const float*)d_in[2];
    const float* Wci = (const float*)d_in[3];
    const float* Wcf = (const float*)d_in[4];
    const float* Wco = (const float*)d_in[5];
    float* out = (float*)d_out;

    dim3 grid(16, COUT, BB);   // 4x4 spatial tiles, 64 cout, 4 batch
    convqrnn_fused<<<grid, 256, 0, stream>>>(X, Wc, bc, Wci, Wcf, Wco, out);
}

// Round 2
// 505.425 us; speedup vs baseline: 1.6032x; 1.6032x over previous
//
#include <hip/hip_runtime.h>

#define TT     32
#define HW     4096           // 64*64
#define LROW   67             // 66 cols + 1 pad
#define LPLANE (6 * LROW)     // 6 halo rows per cin
#define NSTG   (3 * 6 * 66)   // 1188 staged elements per plane

__device__ __forceinline__ float fsigmoid(float x) {
    return __builtin_amdgcn_rcpf(1.0f + __builtin_amdgcn_exp2f(x * -1.4426950408889634f));
}
__device__ __forceinline__ float ftanh(float x) {
    return 2.0f * __builtin_amdgcn_rcpf(1.0f + __builtin_amdgcn_exp2f(x * -2.8853900817779268f)) - 1.0f;
}

__global__ __launch_bounds__(256, 2) void convqrnn(
    const float* __restrict__ X,    // (4,3,32,64,64)
    const float* __restrict__ Wc,   // (256,3,2,3,3)
    const float* __restrict__ bc,   // (256)
    const float* __restrict__ Wci,  // (64,64,64)
    const float* __restrict__ Wcf,
    const float* __restrict__ Wco,
    float* __restrict__ out)        // (4,64,32,64,64)
{
    __shared__ float sx[3 * LPLANE];   // one time-plane, 3 cin halo tiles
    __shared__ float gb[4 * 256];      // gate exchange: [gate][pixel]

    const int tid = threadIdx.x;
    const int h0  = blockIdx.x * 4;    // 16 row-tiles of height 4, full width
    const int co  = blockIdx.y;
    const int b   = blockIdx.z;

    // gate-compute mapping: wave g handles gate g; lane owns 4 consecutive cols
    const int g  = tid >> 6;
    const int l  = tid & 63;
    const int r  = l >> 4;            // 0..3 tile row
    const int c0 = (l & 15) * 4;      // col base (0,4,...,60)

    // recurrence-owner mapping: pixel p = tid (4 rows x 64 cols, row-major)
    const int prow = tid >> 6;
    const int pcol = tid & 63;
    const int opix = (h0 + prow) * 64 + pcol;

    const float wci = Wci[co * HW + opix];
    const float wcf = Wcf[co * HW + opix];
    const float wco = Wco[co * HW + opix];

    // conv weights for (gate g, channel co): 54 floats, resident in VGPRs
    float wgt[54];
    {
        const float* __restrict__ wrow = Wc + (size_t)(g * 64 + co) * 54;
        #pragma unroll
        for (int j = 0; j < 54; ++j) wgt[j] = wrow[j];
    }
    const float bg = bc[g * 64 + co];

    // ---- staging precompute: 5 chunks of 256 covering 3x6x66 halo tile ----
    const float* __restrict__ Xb = X + (size_t)b * (3 * TT * HW);
    int  soff[5];
    int  goff[5];
    bool sval[5];
    #pragma unroll
    for (int k = 0; k < 5; ++k) {
        int idx  = tid + k * 256;
        bool inr = (idx < NSTG);
        int idc  = inr ? idx : 0;
        int ci   = idc / 396;              // 6*66
        int rem  = idc - ci * 396;
        int y    = rem / 66;
        int x    = rem - y * 66;
        int gh   = h0 + y - 1;
        int gw   = x - 1;
        bool v   = inr && (gh >= 0) && (gh < 64) && (gw >= 0) && (gw < 64);
        int ghc  = gh < 0 ? 0 : (gh > 63 ? 63 : gh);
        int gwc  = gw < 0 ? 0 : (gw > 63 ? 63 : gw);
        soff[k]  = inr ? (ci * LPLANE + y * LROW + x) : (LROW - 1); // dummy pad slot
        goff[k]  = ci * (TT * HW) + ghc * 64 + gwc;                 // plane 0
        sval[k]  = v;
    }

    // prologue: stage plane t=0
    #pragma unroll
    for (int k = 0; k < 5; ++k) {
        float v = sval[k] ? Xb[goff[k]] : 0.0f;
        sx[soff[k]] = v;
        goff[k] += HW;                       // -> plane 1
    }

    // output addressing (scalar base + 32-bit vector offset)
    float* __restrict__ outb = out + (size_t)(b * 64 + co) * (TT * HW);
    int ooff = opix;

    float s0c0 = 0.f, s0c1 = 0.f, s0c2 = 0.f, s0c3 = 0.f;  // dt=0 partial carry
    float C = 0.f;

    for (int t = 0; t < TT; ++t) {
        __syncthreads();   // staged plane t visible; prev-iter gb reads done

        // window: 3 cin x 3 rows x 6 cols from LDS
        float win[3][3][6];
        #pragma unroll
        for (int ci = 0; ci < 3; ++ci)
            #pragma unroll
            for (int kh = 0; kh < 3; ++kh)
                #pragma unroll
                for (int j = 0; j < 6; ++j)
                    win[ci][kh][j] = sx[ci * LPLANE + (r + kh) * LROW + c0 + j];

        // prefetch next plane's staging values (VMEM overlaps FMAs)
        float stv[5];
        {
            const bool live = (t < TT - 1);
            #pragma unroll
            for (int k = 0; k < 5; ++k) {
                stv[k] = (sval[k] && live) ? Xb[goff[k]] : 0.0f;
                goff[k] += HW;
            }
        }

        // conv: s1 = dt=1 taps on plane t; n = dt=0 taps on plane t (used at t+1)
        float s10 = bg, s11 = bg, s12 = bg, s13 = bg;
        float n0 = 0.f, n1 = 0.f, n2 = 0.f, n3 = 0.f;
        #pragma unroll
        for (int ci = 0; ci < 3; ++ci)
            #pragma unroll
            for (int kh = 0; kh < 3; ++kh)
                #pragma unroll
                for (int kw = 0; kw < 3; ++kw) {
                    const float wp = wgt[ci * 18 +     kh * 3 + kw];
                    const float wc = wgt[ci * 18 + 9 + kh * 3 + kw];
                    s10 += wc * win[ci][kh][kw + 0];
                    s11 += wc * win[ci][kh][kw + 1];
                    s12 += wc * win[ci][kh][kw + 2];
                    s13 += wc * win[ci][kh][kw + 3];
                    n0  += wp * win[ci][kh][kw + 0];
                    n1  += wp * win[ci][kh][kw + 1];
                    n2  += wp * win[ci][kh][kw + 2];
                    n3  += wp * win[ci][kh][kw + 3];
                }

        float4 gv = make_float4(s10 + s0c0, s11 + s0c1, s12 + s0c2, s13 + s0c3);
        s0c0 = n0; s0c1 = n1; s0c2 = n2; s0c3 = n3;
        *(float4*)&gb[g * 256 + r * 64 + c0] = gv;

        __syncthreads();   // gates visible; all win reads of plane t done

        // recurrence: owner thread per pixel
        const float iv = gb[tid];
        const float fv = gb[256 + tid];
        const float gg = gb[512 + tid];
        const float ov = gb[768 + tid];
        const float ig = fsigmoid(iv + wci * C);
        const float fg = fsigmoid(fv + wcf * C);
        const float Cn = fg * C + ig * ftanh(gg);
        const float og = fsigmoid(ov + wco * Cn);
        outb[ooff] = og * ftanh(Cn);
        ooff += HW;
        C = Cn;

        // commit staged plane t+1 (distinct LDS region from gb)
        #pragma unroll
        for (int k = 0; k < 5; ++k) sx[soff[k]] = stv[k];
    }
}

extern "C" void kernel_launch(void* const* d_in, const int* in_sizes, int n_in,
                              void* d_out, int out_size, void* d_ws, size_t ws_size,
                              hipStream_t stream) {
    const float* X   = (const float*)d_in[0];
    const float* Wc  = (const float*)d_in[1];
    const float* bc  = (const float*)d_in[2];
    const float* Wci = (const float*)d_in[3];
    const float* Wcf = (const float*)d_in[4];
    const float* Wco = (const float*)d_in[5];
    float* out = (float*)d_out;

    dim3 grid(16, 64, 4);   // row-tiles, cout, batch
    convqrnn<<<grid, 256, 0, stream>>>(X, Wc, bc, Wci, Wcf, Wco, out);
}